// Round 2
// baseline (2402.488 us; speedup 1.0000x reference)
//
#include <hip/hip_runtime.h>
#include <math.h>

#define BB 4
#define SP 6272      // 28*28*8 spatial per batch
#define NSP 25088    // BB*SP
#define EPS 1e-5f

// ---------------- conv3d 3x3x3 pad1 + bias (+relu) (+BN stats) ----------------
// grid.x = 98 (98*256 == 25088 exactly), grid.y = COUT/OT. Thread = one spatial
// position, OT output channels in registers. launch_bounds(256,4) -> 128 VGPR
// budget so off[27]/msk[27]/xv[27] stay in registers (R1 showed 64-VGPR spill
// thrash: 31.9ms dispatch, 126MB scratch FETCH).
template<int CIN, int COUT, int OT, bool RELU, bool STATS>
__global__ __launch_bounds__(256, 4) void conv3x3(const float* __restrict__ X,
        const float* __restrict__ Wt, const float* __restrict__ bias,
        float* __restrict__ Y, float* __restrict__ s_sum, float* __restrict__ s_sq)
{
    int s = blockIdx.x * 256 + threadIdx.x;   // [0, NSP)
    int b = s / SP;
    int sp = s - b * SP;
    int d = sp / 224;
    int r = sp - d * 224;
    int h = r >> 3;
    int w = r & 7;
    int o0 = blockIdx.y * OT;

    int off[27]; float msk[27];
    #pragma unroll
    for (int t = 0; t < 27; t++) {
        int kd = t / 9 - 1, kh = (t / 3) % 3 - 1, kw = t % 3 - 1;
        int dd = d + kd, hh = h + kh, ww = w + kw;
        bool v = (unsigned)dd < 28u && (unsigned)hh < 28u && (unsigned)ww < 8u;
        off[t] = v ? (dd * 224 + hh * 8 + ww) : 0;
        msk[t] = v ? 1.f : 0.f;
    }
    float acc[OT];
    #pragma unroll
    for (int oo = 0; oo < OT; oo++) acc[oo] = bias[o0 + oo];

    const float* xb = X + (size_t)b * CIN * SP;
    for (int c = 0; c < CIN; c++) {
        const float* xc = xb + (size_t)c * SP;
        float xv[27];
        #pragma unroll
        for (int t = 0; t < 27; t++) xv[t] = xc[off[t]] * msk[t];
        #pragma unroll
        for (int oo = 0; oo < OT; oo++) {
            const float* wp = Wt + ((size_t)(o0 + oo) * CIN + c) * 27;
            #pragma unroll
            for (int t = 0; t < 27; t++) acc[oo] = fmaf(xv[t], wp[t], acc[oo]);
        }
    }
    #pragma unroll
    for (int oo = 0; oo < OT; oo++) {
        float v = acc[oo];
        if (RELU) v = fmaxf(v, 0.f);
        Y[((size_t)b * COUT + o0 + oo) * SP + sp] = v;
        if (STATS) {
            float rs = v, rq = v * v;
            #pragma unroll
            for (int ofs = 32; ofs > 0; ofs >>= 1) {
                rs += __shfl_down(rs, ofs, 64);
                rq += __shfl_down(rq, ofs, 64);
            }
            if ((threadIdx.x & 63) == 0) {
                atomicAdd(&s_sum[o0 + oo], rs);
                atomicAdd(&s_sq[o0 + oo], rq);
            }
        }
    }
}

// ---------------- BN apply (training-mode, biased var), in-place ----------------
// WRT: also write channel-minor transpose h3t[b][sp][c] for the deform gather.
template<bool WRT>
__global__ __launch_bounds__(256) void bn_apply(float* __restrict__ Y,
        const float* __restrict__ s_sum, const float* __restrict__ s_sq,
        const float* __restrict__ g, const float* __restrict__ bb,
        int C, float* __restrict__ Yt)
{
    int idx = blockIdx.x * 256 + threadIdx.x;
    int sp = idx % SP;
    int bc = idx / SP;
    int c = bc % C;
    int b = bc / C;
    float m  = s_sum[c] * (1.f / NSP);
    float v  = s_sq[c] * (1.f / NSP) - m * m;
    float sc = g[c] * rsqrtf(v + EPS);
    float val = (Y[idx] - m) * sc + bb[c];
    Y[idx] = val;
    if (WRT) Yt[((size_t)b * SP + sp) * 128 + c] = val;
}

// ---------------- deform weight transpose: dw[o][c][n] -> dwt[n][c][o] ----------------
__global__ __launch_bounds__(256) void transpose_dw(const float* __restrict__ dw,
                                                    float* __restrict__ dwt)
{
    int idx = blockIdx.x * 256 + threadIdx.x;   // 27*128*128 = 442368 = 1728*256
    int n = idx / 16384;
    int r = idx % 16384;
    int c = r >> 7;
    int o = r & 127;
    dwt[idx] = dw[((size_t)o * 128 + c) * 27 + n];
}

// ---------------- deformable conv + bias + relu + pooled/stat accumulation ----------------
// Block = (b, d, h-quad): 32 spatial positions x 128 output channels.
// Phase roles per n: geometry (1 thread per (p,corner)), sampling V[c][p]
// (coalesced across c), GEMM with 2 o x 8 p per thread (16 FMA per 2 weight
// loads + 2 broadcast ds_read_b128). y4 never materialized.
__global__ __launch_bounds__(256) void deform_pool(const float* __restrict__ Ht,
        const float* __restrict__ OFF, const float* __restrict__ dwt,
        const float* __restrict__ db, float* __restrict__ pooledraw,
        float* __restrict__ sumsq4)
{
    __shared__ int   idx_s[32][8];
    __shared__ float g_s[32][8];
    __shared__ __align__(16) float Vb[128 * 36];   // [c][p] rows padded 32->36 (16B aligned)
    __shared__ float reds[128], redq[128];

    int t = threadIdx.x;
    int b = blockIdx.y;
    int d = blockIdx.x / 7;
    int h0 = (blockIdx.x % 7) * 4;

    // geometry role: p = gp (lh*8+w), corner gcr
    int gp = t >> 3, gcr = t & 7;
    int glh = gp >> 3, gw = gp & 7, gh = h0 + glh;
    // phase2 role: channel c2, p-half
    int c2 = t & 127, half = t >> 7;
    // phase3 role: lane l -> outputs {l, l+64}, wave wv -> p-octet
    int l = t & 63, wvid = t >> 6;

    float acc0[8], acc1[8];
    #pragma unroll
    for (int i = 0; i < 8; i++) { acc0[i] = 0.f; acc1[i] = 0.f; }

    const float* hb = Ht + (size_t)b * SP * 128;

    for (int n = 0; n < 27; n++) {
        __syncthreads();   // prev phase3 done with Vb, prev phase2 done with geom
        {   // ---- geometry for (n, gp, gcr) ----
            int kd = n / 9 - 1, kh = (n / 3) % 3 - 1, kw = n % 3 - 1;
            size_t obase = (size_t)b * 81 * SP + (size_t)d * 224 + gh * 8 + gw;
            float od  = OFF[obase + (size_t)n * SP];
            float oh  = OFF[obase + (size_t)(27 + n) * SP];
            float owv = OFF[obase + (size_t)(54 + n) * SP];
            float pd = fminf(fmaxf((float)(d + 1 + kd) + od, 0.f), 29.f);
            float ph = fminf(fmaxf((float)(gh + 1 + kh) + oh, 0.f), 29.f);
            float pw = fminf(fmaxf((float)(gw + 1 + kw) + owv, 0.f), 9.f);
            float qd = fminf(floorf(pd), 28.f);
            float qh = fminf(floorf(ph), 28.f);
            float qw = fminf(floorf(pw), 8.f);
            float td = fminf(pd - qd, 1.f);
            float th = fminf(ph - qh, 1.f);
            float tw = fminf(pw - qw, 1.f);
            int iqd = (int)qd - 1, iqh = (int)qh - 1, iqw = (int)qw - 1;
            int i = gcr >> 2, j = (gcr >> 1) & 1, k = gcr & 1;
            int du = iqd + i, hu = iqh + j, wu = iqw + k;
            bool val = (unsigned)du < 28u && (unsigned)hu < 28u && (unsigned)wu < 8u;
            float gg = (i ? td : 1.f - td) * (j ? th : 1.f - th) * (k ? tw : 1.f - tw);
            idx_s[gp][gcr] = val ? (du * 224 + hu * 8 + wu) : 0;
            g_s[gp][gcr] = val ? gg : 0.f;   // pad corners contribute 0 (ref pads with 0)
        }
        __syncthreads();
        // ---- phase 2: V[c][p] trilinear sample, coalesced across c ----
        float vloc[16];
        #pragma unroll
        for (int q = 0; q < 16; q++) {
            int p = half * 16 + q;
            float v = 0.f;
            #pragma unroll
            for (int cr = 0; cr < 8; cr++) {
                int id = idx_s[p][cr];
                float gg = g_s[p][cr];
                v = fmaf(gg, hb[(size_t)id * 128 + c2], v);
            }
            vloc[q] = v;
        }
        float4* dst = (float4*)&Vb[c2 * 36 + half * 16];
        dst[0] = make_float4(vloc[0],  vloc[1],  vloc[2],  vloc[3]);
        dst[1] = make_float4(vloc[4],  vloc[5],  vloc[6],  vloc[7]);
        dst[2] = make_float4(vloc[8],  vloc[9],  vloc[10], vloc[11]);
        dst[3] = make_float4(vloc[12], vloc[13], vloc[14], vloc[15]);
        __syncthreads();
        // ---- phase 3: out[o][p] += sum_c dwt[n][c][o] * V[c][p] ----
        const float* wp = dwt + (size_t)n * 16384 + l;
        #pragma unroll 4
        for (int c = 0; c < 128; c++) {
            float w0 = wp[(size_t)c * 128];
            float w1 = wp[(size_t)c * 128 + 64];
            float4 va = *(const float4*)&Vb[c * 36 + wvid * 8];
            float4 vb4 = *(const float4*)&Vb[c * 36 + wvid * 8 + 4];
            acc0[0] = fmaf(w0, va.x, acc0[0]);   acc1[0] = fmaf(w1, va.x, acc1[0]);
            acc0[1] = fmaf(w0, va.y, acc0[1]);   acc1[1] = fmaf(w1, va.y, acc1[1]);
            acc0[2] = fmaf(w0, va.z, acc0[2]);   acc1[2] = fmaf(w1, va.z, acc1[2]);
            acc0[3] = fmaf(w0, va.w, acc0[3]);   acc1[3] = fmaf(w1, va.w, acc1[3]);
            acc0[4] = fmaf(w0, vb4.x, acc0[4]);  acc1[4] = fmaf(w1, vb4.x, acc1[4]);
            acc0[5] = fmaf(w0, vb4.y, acc0[5]);  acc1[5] = fmaf(w1, vb4.y, acc1[5]);
            acc0[6] = fmaf(w0, vb4.z, acc0[6]);  acc1[6] = fmaf(w1, vb4.z, acc1[6]);
            acc0[7] = fmaf(w0, vb4.w, acc0[7]);  acc1[7] = fmaf(w1, vb4.w, acc1[7]);
        }
    }

    // ---- epilogue: bias + relu + pooled sum / sumsq ----
    float bo0 = db[l], bo1 = db[l + 64];
    float s0 = 0.f, q0 = 0.f, s1 = 0.f, q1 = 0.f;
    #pragma unroll
    for (int i = 0; i < 8; i++) {
        float v0 = fmaxf(acc0[i] + bo0, 0.f);
        float v1 = fmaxf(acc1[i] + bo1, 0.f);
        s0 += v0; q0 += v0 * v0;
        s1 += v1; q1 += v1 * v1;
    }
    __syncthreads();
    if (t < 128) { reds[t] = 0.f; redq[t] = 0.f; }
    __syncthreads();
    atomicAdd(&reds[l], s0);       atomicAdd(&redq[l], q0);
    atomicAdd(&reds[l + 64], s1);  atomicAdd(&redq[l + 64], q1);
    __syncthreads();
    if (t < 128) {
        atomicAdd(&pooledraw[b * 128 + t], reds[t]);
        atomicAdd(&sumsq4[t], redq[t]);
    }
}

// ---------------- BN4-folded pooling + FC + log_softmax ----------------
__global__ __launch_bounds__(256) void final_head(const float* __restrict__ pooledraw,
        const float* __restrict__ sumsq4, const float* __restrict__ g4,
        const float* __restrict__ b4, const float* __restrict__ fcw,
        const float* __restrict__ fcb, float* __restrict__ out)
{
    __shared__ float pooled_s[4][128];
    __shared__ float logits[4][10];
    int t = threadIdx.x;
    if (t < 128) {
        float s0 = pooledraw[t], s1 = pooledraw[128 + t];
        float s2 = pooledraw[256 + t], s3 = pooledraw[384 + t];
        float tot = s0 + s1 + s2 + s3;
        float m  = tot * (1.f / NSP);
        float v  = sumsq4[t] * (1.f / NSP) - m * m;
        float sc = g4[t] * rsqrtf(v + EPS);
        float sh = b4[t] - m * sc;
        pooled_s[0][t] = s0 * (1.f / SP) * sc + sh;
        pooled_s[1][t] = s1 * (1.f / SP) * sc + sh;
        pooled_s[2][t] = s2 * (1.f / SP) * sc + sh;
        pooled_s[3][t] = s3 * (1.f / SP) * sc + sh;
    }
    __syncthreads();
    if (t < 40) {
        int b = t / 10, j = t % 10;
        float l = fcb[j];
        for (int c = 0; c < 128; c++) l = fmaf(pooled_s[b][c], fcw[j * 128 + c], l);
        logits[b][j] = l;
    }
    __syncthreads();
    if (t < 4) {
        float mx = -1e30f;
        for (int j = 0; j < 10; j++) mx = fmaxf(mx, logits[t][j]);
        float se = 0.f;
        for (int j = 0; j < 10; j++) se += expf(logits[t][j] - mx);
        float lse = mx + logf(se);
        for (int j = 0; j < 10; j++) out[t * 10 + j] = logits[t][j] - lse;
    }
}

extern "C" void kernel_launch(void* const* d_in, const int* in_sizes, int n_in,
                              void* d_out, int out_size, void* d_ws, size_t ws_size,
                              hipStream_t stream)
{
    (void)in_sizes; (void)n_in; (void)out_size; (void)ws_size;
    const float* x   = (const float*)d_in[0];
    const float* c1w = (const float*)d_in[1];
    const float* c1b = (const float*)d_in[2];
    const float* g1  = (const float*)d_in[3];
    const float* b1  = (const float*)d_in[4];
    const float* c2w = (const float*)d_in[5];
    const float* c2b = (const float*)d_in[6];
    const float* g2  = (const float*)d_in[7];
    const float* b2  = (const float*)d_in[8];
    const float* c3w = (const float*)d_in[9];
    const float* c3b = (const float*)d_in[10];
    const float* g3  = (const float*)d_in[11];
    const float* b3  = (const float*)d_in[12];
    const float* ow  = (const float*)d_in[13];
    const float* ob  = (const float*)d_in[14];
    const float* dw  = (const float*)d_in[15];
    const float* db  = (const float*)d_in[16];
    const float* g4  = (const float*)d_in[17];
    const float* b4  = (const float*)d_in[18];
    const float* fcw = (const float*)d_in[19];
    const float* fcb = (const float*)d_in[20];

    float* ws = (float*)d_ws;
    float* S1 = ws + 0,   *Q1 = ws + 32;
    float* S2 = ws + 96,  *Q2 = ws + 160;
    float* S3 = ws + 224, *Q3 = ws + 352;
    float* PO = ws + 480;   // 4*128
    float* Q4 = ws + 992;   // 128
    float* y1  = ws + 2048;            // 4*32*6272
    float* y2  = y1 + 802816;          // 4*64*6272
    float* y3  = y2 + 1605632;         // 4*128*6272
    float* h3t = y3 + 3211264;         // channel-minor copy of h3
    float* dwt = h3t + 3211264;        // 27*128*128

    float* outf = (float*)d_out;
    float* offs = outf + 40;           // second output: offsets (4,81,28,28,8)

    hipMemsetAsync(ws, 0, 2048 * sizeof(float), stream);
    transpose_dw<<<1728, 256, 0, stream>>>(dw, dwt);

    conv3x3<1, 32, 8, true, true><<<dim3(98, 4), 256, 0, stream>>>(x, c1w, c1b, y1, S1, Q1);
    bn_apply<false><<<3136, 256, 0, stream>>>(y1, S1, Q1, g1, b1, 32, nullptr);

    conv3x3<32, 64, 8, true, true><<<dim3(98, 8), 256, 0, stream>>>(y1, c2w, c2b, y2, S2, Q2);
    bn_apply<false><<<6272, 256, 0, stream>>>(y2, S2, Q2, g2, b2, 64, nullptr);

    conv3x3<64, 128, 8, true, true><<<dim3(98, 16), 256, 0, stream>>>(y2, c3w, c3b, y3, S3, Q3);
    bn_apply<true><<<12544, 256, 0, stream>>>(y3, S3, Q3, g3, b3, 128, h3t);

    conv3x3<128, 81, 9, false, false><<<dim3(98, 9), 256, 0, stream>>>(y3, ow, ob, offs,
                                                                        nullptr, nullptr);
    deform_pool<<<dim3(196, 4), 256, 0, stream>>>(h3t, offs, dwt, db, PO, Q4);
    final_head<<<1, 256, 0, stream>>>(PO, Q4, g4, b4, fcw, fcb, outf);
}

// Round 3
// 2016.495 us; speedup vs baseline: 1.1914x; 1.1914x over previous
//
#include <hip/hip_runtime.h>
#include <math.h>

#define BB 4
#define SP 6272      // 28*28*8 spatial per batch
#define NSP 25088    // BB*SP
#define EPS 1e-5f

// ---------------- conv3d 3x3x3 pad1 + bias (+relu) (+BN stats) ----------------
// Thread = one spatial position (lane = w), OT output channels in registers.
// w-taps via 1 load + 2 shuffles (row-crossing lanes are masked by mw0/mw2).
// amdgpu_waves_per_eu(1,4): cap occupancy at 4 waves/EU -> 128-VGPR budget so
// the allocator does NOT spill (R1/R2 showed 64-VGPR scratch thrash: 57 MB
// FETCH per dispatch, VALUBusy 15%).
template<int CIN, int COUT, int OT, bool RELU, bool STATS>
__global__ __launch_bounds__(256) __attribute__((amdgpu_waves_per_eu(1, 4)))
void conv3x3(const float* __restrict__ X,
        const float* __restrict__ Wt, const float* __restrict__ bias,
        float* __restrict__ Y, float* __restrict__ s_sum, float* __restrict__ s_sq)
{
    int s = blockIdx.x * 256 + threadIdx.x;   // [0, NSP)
    int b = s / SP;
    int sp = s - b * SP;
    int d = sp / 224;
    int r = sp - d * 224;
    int h = r >> 3;
    int w = r & 7;
    int o0 = blockIdx.y * OT;

    float mdh[9]; int odh[9];
    #pragma unroll
    for (int i = 0; i < 3; i++) {
        int dd = d + i - 1;
        float md = ((unsigned)dd < 28u) ? 1.f : 0.f;
        int ddc = min(max(dd, 0), 27);
        #pragma unroll
        for (int j = 0; j < 3; j++) {
            int hh = h + j - 1;
            float mh = ((unsigned)hh < 28u) ? 1.f : 0.f;
            int hhc = min(max(hh, 0), 27);
            mdh[i * 3 + j] = md * mh;
            odh[i * 3 + j] = ddc * 224 + hhc * 8 + w;
        }
    }
    float mw0 = (w > 0) ? 1.f : 0.f;
    float mw2 = (w < 7) ? 1.f : 0.f;

    float acc[OT];
    #pragma unroll
    for (int oo = 0; oo < OT; oo++) acc[oo] = bias[o0 + oo];

    const float* xb = X + (size_t)b * CIN * SP;
    const float* wb = Wt + (size_t)o0 * CIN * 27;
    for (int c = 0; c < CIN; c++) {
        const float* xc = xb + (size_t)c * SP;
        #pragma unroll
        for (int t9 = 0; t9 < 9; t9++) {
            float x0 = xc[odh[t9]];
            float m = mdh[t9];
            float xm = __shfl_up(x0, 1, 64) * (m * mw0);
            float xz = x0 * m;
            float xp = __shfl_down(x0, 1, 64) * (m * mw2);
            #pragma unroll
            for (int oo = 0; oo < OT; oo++) {
                const float* wp = wb + ((size_t)oo * CIN + c) * 27 + t9 * 3;
                acc[oo] = fmaf(xm, wp[0], acc[oo]);
                acc[oo] = fmaf(xz, wp[1], acc[oo]);
                acc[oo] = fmaf(xp, wp[2], acc[oo]);
            }
        }
    }
    #pragma unroll
    for (int oo = 0; oo < OT; oo++) {
        float v = acc[oo];
        if (RELU) v = fmaxf(v, 0.f);
        Y[((size_t)b * COUT + o0 + oo) * SP + sp] = v;
        if (STATS) {
            float rs = v, rq = v * v;
            #pragma unroll
            for (int ofs = 32; ofs > 0; ofs >>= 1) {
                rs += __shfl_down(rs, ofs, 64);
                rq += __shfl_down(rq, ofs, 64);
            }
            if ((threadIdx.x & 63) == 0) {
                atomicAdd(&s_sum[o0 + oo], rs);
                atomicAdd(&s_sq[o0 + oo], rq);
            }
        }
    }
}

// ---------------- BN apply (training-mode, biased var), in-place ----------------
template<bool WRT>
__global__ __launch_bounds__(256) void bn_apply(float* __restrict__ Y,
        const float* __restrict__ s_sum, const float* __restrict__ s_sq,
        const float* __restrict__ g, const float* __restrict__ bb,
        int C, float* __restrict__ Yt)
{
    int idx = blockIdx.x * 256 + threadIdx.x;
    int sp = idx % SP;
    int bc = idx / SP;
    int c = bc % C;
    int b = bc / C;
    float m  = s_sum[c] * (1.f / NSP);
    float v  = s_sq[c] * (1.f / NSP) - m * m;
    float sc = g[c] * rsqrtf(v + EPS);
    float val = (Y[idx] - m) * sc + bb[c];
    Y[idx] = val;
    if (WRT) Yt[((size_t)b * SP + sp) * 128 + c] = val;
}

// ---------------- deform weight transpose: dw[o][c][n] -> dwt[n][c][o] ----------------
__global__ __launch_bounds__(256) void transpose_dw(const float* __restrict__ dw,
                                                    float* __restrict__ dwt)
{
    int idx = blockIdx.x * 256 + threadIdx.x;   // 27*128*128 = 442368 = 1728*256
    int n = idx / 16384;
    int r = idx % 16384;
    int c = r >> 7;
    int o = r & 127;
    dwt[idx] = dw[((size_t)o * 128 + c) * 27 + n];
}

// ---------------- deformable conv + bias + relu + pooled/stat accumulation ----------------
// Block = (b, d, h-quad): 32 spatial positions x 128 output channels.
// Per n: geometry -> V[c][p] sampling (coalesced across c) -> GEMM 2o x 8p per
// thread (16 FMA per 2 coalesced weight loads + 2 broadcast ds_read_b128).
// waves_per_eu(1,4) -> 128-VGPR budget for the 16 accumulators (R2 spilled at 64).
__global__ __launch_bounds__(256) __attribute__((amdgpu_waves_per_eu(1, 4)))
void deform_pool(const float* __restrict__ Ht,
        const float* __restrict__ OFF, const float* __restrict__ dwt,
        const float* __restrict__ db, float* __restrict__ pooledraw,
        float* __restrict__ sumsq4)
{
    __shared__ int   idx_s[32][8];
    __shared__ float g_s[32][8];
    __shared__ __align__(16) float Vb[128 * 36];   // [c][p], rows padded 32->36
    __shared__ float reds[128], redq[128];

    int t = threadIdx.x;
    int b = blockIdx.y;
    int d = blockIdx.x / 7;
    int h0 = (blockIdx.x % 7) * 4;

    int gp = t >> 3, gcr = t & 7;                 // geometry role
    int glh = gp >> 3, gw = gp & 7, gh = h0 + glh;
    int c2 = t & 127, half = t >> 7;              // phase2 role
    int l = t & 63, wvid = t >> 6;                // phase3 role

    float acc0[8], acc1[8];
    #pragma unroll
    for (int i = 0; i < 8; i++) { acc0[i] = 0.f; acc1[i] = 0.f; }

    const float* hb = Ht + (size_t)b * SP * 128;

    for (int n = 0; n < 27; n++) {
        __syncthreads();   // prev phase3 done with Vb / geom
        {   // ---- geometry for (n, gp, gcr) ----
            int kd = n / 9 - 1, kh = (n / 3) % 3 - 1, kw = n % 3 - 1;
            size_t obase = (size_t)b * 81 * SP + (size_t)d * 224 + gh * 8 + gw;
            float od  = OFF[obase + (size_t)n * SP];
            float oh  = OFF[obase + (size_t)(27 + n) * SP];
            float owv = OFF[obase + (size_t)(54 + n) * SP];
            float pd = fminf(fmaxf((float)(d + 1 + kd) + od, 0.f), 29.f);
            float ph = fminf(fmaxf((float)(gh + 1 + kh) + oh, 0.f), 29.f);
            float pw = fminf(fmaxf((float)(gw + 1 + kw) + owv, 0.f), 9.f);
            float qd = fminf(floorf(pd), 28.f);
            float qh = fminf(floorf(ph), 28.f);
            float qw = fminf(floorf(pw), 8.f);
            float td = fminf(pd - qd, 1.f);
            float th = fminf(ph - qh, 1.f);
            float tw = fminf(pw - qw, 1.f);
            int iqd = (int)qd - 1, iqh = (int)qh - 1, iqw = (int)qw - 1;
            int i = gcr >> 2, j = (gcr >> 1) & 1, k = gcr & 1;
            int du = iqd + i, hu = iqh + j, wu = iqw + k;
            bool val = (unsigned)du < 28u && (unsigned)hu < 28u && (unsigned)wu < 8u;
            float gg = (i ? td : 1.f - td) * (j ? th : 1.f - th) * (k ? tw : 1.f - tw);
            idx_s[gp][gcr] = val ? (du * 224 + hu * 8 + wu) : 0;
            g_s[gp][gcr] = val ? gg : 0.f;   // pad corners contribute 0
        }
        __syncthreads();
        // ---- phase 2: V[c][p] trilinear sample, coalesced across c ----
        #pragma unroll
        for (int q4 = 0; q4 < 4; q4++) {
            float v4[4];
            #pragma unroll
            for (int q = 0; q < 4; q++) {
                int p = half * 16 + q4 * 4 + q;
                float v = 0.f;
                #pragma unroll
                for (int cr = 0; cr < 8; cr++) {
                    int id = idx_s[p][cr];
                    float gg = g_s[p][cr];
                    v = fmaf(gg, hb[(size_t)id * 128 + c2], v);
                }
                v4[q] = v;
            }
            *(float4*)&Vb[c2 * 36 + half * 16 + q4 * 4] =
                make_float4(v4[0], v4[1], v4[2], v4[3]);
        }
        __syncthreads();
        // ---- phase 3: out[o][p] += sum_c dwt[n][c][o] * V[c][p] ----
        const float* wp = dwt + (size_t)n * 16384 + l;
        #pragma unroll 4
        for (int c = 0; c < 128; c++) {
            float w0 = wp[(size_t)c * 128];
            float w1 = wp[(size_t)c * 128 + 64];
            float4 va  = *(const float4*)&Vb[c * 36 + wvid * 8];
            float4 vb4 = *(const float4*)&Vb[c * 36 + wvid * 8 + 4];
            acc0[0] = fmaf(w0, va.x, acc0[0]);   acc1[0] = fmaf(w1, va.x, acc1[0]);
            acc0[1] = fmaf(w0, va.y, acc0[1]);   acc1[1] = fmaf(w1, va.y, acc1[1]);
            acc0[2] = fmaf(w0, va.z, acc0[2]);   acc1[2] = fmaf(w1, va.z, acc1[2]);
            acc0[3] = fmaf(w0, va.w, acc0[3]);   acc1[3] = fmaf(w1, va.w, acc1[3]);
            acc0[4] = fmaf(w0, vb4.x, acc0[4]);  acc1[4] = fmaf(w1, vb4.x, acc1[4]);
            acc0[5] = fmaf(w0, vb4.y, acc0[5]);  acc1[5] = fmaf(w1, vb4.y, acc1[5]);
            acc0[6] = fmaf(w0, vb4.z, acc0[6]);  acc1[6] = fmaf(w1, vb4.z, acc1[6]);
            acc0[7] = fmaf(w0, vb4.w, acc0[7]);  acc1[7] = fmaf(w1, vb4.w, acc1[7]);
        }
    }

    // ---- epilogue: bias + relu + pooled sum / sumsq ----
    float bo0 = db[l], bo1 = db[l + 64];
    float s0 = 0.f, q0 = 0.f, s1 = 0.f, q1 = 0.f;
    #pragma unroll
    for (int i = 0; i < 8; i++) {
        float v0 = fmaxf(acc0[i] + bo0, 0.f);
        float v1 = fmaxf(acc1[i] + bo1, 0.f);
        s0 += v0; q0 += v0 * v0;
        s1 += v1; q1 += v1 * v1;
    }
    __syncthreads();
    if (t < 128) { reds[t] = 0.f; redq[t] = 0.f; }
    __syncthreads();
    atomicAdd(&reds[l], s0);       atomicAdd(&redq[l], q0);
    atomicAdd(&reds[l + 64], s1);  atomicAdd(&redq[l + 64], q1);
    __syncthreads();
    if (t < 128) {
        atomicAdd(&pooledraw[b * 128 + t], reds[t]);
        atomicAdd(&sumsq4[t], redq[t]);
    }
}

// ---------------- BN4-folded pooling + FC + log_softmax ----------------
__global__ __launch_bounds__(256) void final_head(const float* __restrict__ pooledraw,
        const float* __restrict__ sumsq4, const float* __restrict__ g4,
        const float* __restrict__ b4, const float* __restrict__ fcw,
        const float* __restrict__ fcb, float* __restrict__ out)
{
    __shared__ float pooled_s[4][128];
    __shared__ float logits[4][10];
    int t = threadIdx.x;
    if (t < 128) {
        float s0 = pooledraw[t], s1 = pooledraw[128 + t];
        float s2 = pooledraw[256 + t], s3 = pooledraw[384 + t];
        float tot = s0 + s1 + s2 + s3;
        float m  = tot * (1.f / NSP);
        float v  = sumsq4[t] * (1.f / NSP) - m * m;
        float sc = g4[t] * rsqrtf(v + EPS);
        float sh = b4[t] - m * sc;
        pooled_s[0][t] = s0 * (1.f / SP) * sc + sh;
        pooled_s[1][t] = s1 * (1.f / SP) * sc + sh;
        pooled_s[2][t] = s2 * (1.f / SP) * sc + sh;
        pooled_s[3][t] = s3 * (1.f / SP) * sc + sh;
    }
    __syncthreads();
    if (t < 40) {
        int b = t / 10, j = t % 10;
        float l = fcb[j];
        for (int c = 0; c < 128; c++) l = fmaf(pooled_s[b][c], fcw[j * 128 + c], l);
        logits[b][j] = l;
    }
    __syncthreads();
    if (t < 4) {
        float mx = -1e30f;
        for (int j = 0; j < 10; j++) mx = fmaxf(mx, logits[t][j]);
        float se = 0.f;
        for (int j = 0; j < 10; j++) se += expf(logits[t][j] - mx);
        float lse = mx + logf(se);
        for (int j = 0; j < 10; j++) out[t * 10 + j] = logits[t][j] - lse;
    }
}

extern "C" void kernel_launch(void* const* d_in, const int* in_sizes, int n_in,
                              void* d_out, int out_size, void* d_ws, size_t ws_size,
                              hipStream_t stream)
{
    (void)in_sizes; (void)n_in; (void)out_size; (void)ws_size;
    const float* x   = (const float*)d_in[0];
    const float* c1w = (const float*)d_in[1];
    const float* c1b = (const float*)d_in[2];
    const float* g1  = (const float*)d_in[3];
    const float* b1  = (const float*)d_in[4];
    const float* c2w = (const float*)d_in[5];
    const float* c2b = (const float*)d_in[6];
    const float* g2  = (const float*)d_in[7];
    const float* b2  = (const float*)d_in[8];
    const float* c3w = (const float*)d_in[9];
    const float* c3b = (const float*)d_in[10];
    const float* g3  = (const float*)d_in[11];
    const float* b3  = (const float*)d_in[12];
    const float* ow  = (const float*)d_in[13];
    const float* ob  = (const float*)d_in[14];
    const float* dw  = (const float*)d_in[15];
    const float* db  = (const float*)d_in[16];
    const float* g4  = (const float*)d_in[17];
    const float* b4  = (const float*)d_in[18];
    const float* fcw = (const float*)d_in[19];
    const float* fcb = (const float*)d_in[20];

    float* ws = (float*)d_ws;
    float* S1 = ws + 0,   *Q1 = ws + 32;
    float* S2 = ws + 96,  *Q2 = ws + 160;
    float* S3 = ws + 224, *Q3 = ws + 352;
    float* PO = ws + 480;   // 4*128
    float* Q4 = ws + 992;   // 128
    float* y1  = ws + 2048;            // 4*32*6272
    float* y2  = y1 + 802816;          // 4*64*6272
    float* y3  = y2 + 1605632;         // 4*128*6272
    float* h3t = y3 + 3211264;         // channel-minor copy of h3
    float* dwt = h3t + 3211264;        // 27*128*128

    float* outf = (float*)d_out;
    float* offs = outf + 40;           // second output: offsets (4,81,28,28,8)

    hipMemsetAsync(ws, 0, 2048 * sizeof(float), stream);
    transpose_dw<<<1728, 256, 0, stream>>>(dw, dwt);

    conv3x3<1, 32, 8, true, true><<<dim3(98, 4), 256, 0, stream>>>(x, c1w, c1b, y1, S1, Q1);
    bn_apply<false><<<3136, 256, 0, stream>>>(y1, S1, Q1, g1, b1, 32, nullptr);

    conv3x3<32, 64, 8, true, true><<<dim3(98, 8), 256, 0, stream>>>(y1, c2w, c2b, y2, S2, Q2);
    bn_apply<false><<<6272, 256, 0, stream>>>(y2, S2, Q2, g2, b2, 64, nullptr);

    conv3x3<64, 128, 8, true, true><<<dim3(98, 16), 256, 0, stream>>>(y2, c3w, c3b, y3, S3, Q3);
    bn_apply<true><<<12544, 256, 0, stream>>>(y3, S3, Q3, g3, b3, 128, h3t);

    conv3x3<128, 81, 9, false, false><<<dim3(98, 9), 256, 0, stream>>>(y3, ow, ob, offs,
                                                                        nullptr, nullptr);
    deform_pool<<<dim3(196, 4), 256, 0, stream>>>(h3t, offs, dwt, db, PO, Q4);
    final_head<<<1, 256, 0, stream>>>(PO, Q4, g4, b4, fcw, fcb, outf);
}

// Round 4
// 1918.364 us; speedup vs baseline: 1.2524x; 1.0512x over previous
//
#include <hip/hip_runtime.h>
#include <math.h>

#define BB 4
#define SP 6272      // 28*28*8 spatial per batch
#define NSP 25088    // BB*SP
#define EPS 1e-5f

// ---------------- conv3d 3x3x3 pad1 + bias (+relu) (+BN stats) ----------------
// grid = (104, COUT/OT). XCD swizzle: linear block id % 8 selects XCD (all
// blocks resident -> mapping exact); xcd owns spatial blocks [13*xcd,13*xcd+13)
// for ALL output-channel slices, so the input slab (~1-2 MB incl. halo) stays
// in that XCD's 4 MB L2 instead of being re-fetched per slice (R3: 103 MB
// FETCH on the offset conv = 9 full y3 re-reads).
// w-taps via 1 load + 2 shuffles; waves_per_eu(1,4) -> no spill (R1/R2 lesson).
template<int CIN, int COUT, int OT, bool RELU, bool STATS>
__global__ __launch_bounds__(256) __attribute__((amdgpu_waves_per_eu(1, 4)))
void conv3x3(const float* __restrict__ X,
        const float* __restrict__ Wt, const float* __restrict__ bias,
        float* __restrict__ Y, float* __restrict__ s_sum, float* __restrict__ s_sq)
{
    int xblk = blockIdx.x;                       // [0,104)
    int sblk = (xblk & 7) * 13 + (xblk >> 3);    // contiguous 13-block slab per XCD
    if (sblk >= 98) return;
    int s = sblk * 256 + threadIdx.x;            // [0, NSP)
    int b = s / SP;
    int sp = s - b * SP;
    int d = sp / 224;
    int r = sp - d * 224;
    int h = r >> 3;
    int w = r & 7;
    int o0 = blockIdx.y * OT;

    float mdh[9]; int odh[9];
    #pragma unroll
    for (int i = 0; i < 3; i++) {
        int dd = d + i - 1;
        float md = ((unsigned)dd < 28u) ? 1.f : 0.f;
        int ddc = min(max(dd, 0), 27);
        #pragma unroll
        for (int j = 0; j < 3; j++) {
            int hh = h + j - 1;
            float mh = ((unsigned)hh < 28u) ? 1.f : 0.f;
            int hhc = min(max(hh, 0), 27);
            mdh[i * 3 + j] = md * mh;
            odh[i * 3 + j] = ddc * 224 + hhc * 8 + w;
        }
    }
    float mw0 = (w > 0) ? 1.f : 0.f;
    float mw2 = (w < 7) ? 1.f : 0.f;

    float acc[OT];
    #pragma unroll
    for (int oo = 0; oo < OT; oo++) acc[oo] = bias[o0 + oo];

    const float* xb = X + (size_t)b * CIN * SP;
    const float* wb = Wt + (size_t)o0 * CIN * 27;
    for (int c = 0; c < CIN; c++) {
        const float* xc = xb + (size_t)c * SP;
        #pragma unroll
        for (int t9 = 0; t9 < 9; t9++) {
            float x0 = xc[odh[t9]];
            float m = mdh[t9];
            float xm = __shfl_up(x0, 1, 64) * (m * mw0);
            float xz = x0 * m;
            float xp = __shfl_down(x0, 1, 64) * (m * mw2);
            #pragma unroll
            for (int oo = 0; oo < OT; oo++) {
                const float* wp = wb + ((size_t)oo * CIN + c) * 27 + t9 * 3;
                acc[oo] = fmaf(xm, wp[0], acc[oo]);
                acc[oo] = fmaf(xz, wp[1], acc[oo]);
                acc[oo] = fmaf(xp, wp[2], acc[oo]);
            }
        }
    }
    #pragma unroll
    for (int oo = 0; oo < OT; oo++) {
        float v = acc[oo];
        if (RELU) v = fmaxf(v, 0.f);
        Y[((size_t)b * COUT + o0 + oo) * SP + sp] = v;
        if (STATS) {
            float rs = v, rq = v * v;
            #pragma unroll
            for (int ofs = 32; ofs > 0; ofs >>= 1) {
                rs += __shfl_down(rs, ofs, 64);
                rq += __shfl_down(rq, ofs, 64);
            }
            if ((threadIdx.x & 63) == 0) {
                atomicAdd(&s_sum[o0 + oo], rs);
                atomicAdd(&s_sq[o0 + oo], rq);
            }
        }
    }
}

// ---------------- BN apply (training-mode, biased var), in-place ----------------
template<bool WRT>
__global__ __launch_bounds__(256) void bn_apply(float* __restrict__ Y,
        const float* __restrict__ s_sum, const float* __restrict__ s_sq,
        const float* __restrict__ g, const float* __restrict__ bb,
        int C, float* __restrict__ Yt)
{
    int idx = blockIdx.x * 256 + threadIdx.x;
    int sp = idx % SP;
    int bc = idx / SP;
    int c = bc % C;
    int b = bc / C;
    float m  = s_sum[c] * (1.f / NSP);
    float v  = s_sq[c] * (1.f / NSP) - m * m;
    float sc = g[c] * rsqrtf(v + EPS);
    float val = (Y[idx] - m) * sc + bb[c];
    Y[idx] = val;
    if (WRT) Yt[((size_t)b * SP + sp) * 128 + c] = val;
}

// ---------------- deform weight transpose: dw[o][c][n] -> dwt[n][c][o] ----------------
__global__ __launch_bounds__(256) void transpose_dw(const float* __restrict__ dw,
                                                    float* __restrict__ dwt)
{
    int idx = blockIdx.x * 256 + threadIdx.x;   // 27*128*128 = 442368 = 1728*256
    int n = idx / 16384;
    int r = idx % 16384;
    int c = r >> 7;
    int o = r & 127;
    dwt[idx] = dw[((size_t)o * 128 + c) * 27 + n];
}

// ---------------- deformable conv + bias + relu + pooled/stat accumulation ----------------
// Flat grid 800. XCD swizzle: xcd = fid%8 owns one (batch, d-half) slab, whose
// gather working set (128ch x 17d x 28h x 8w x 4B ~= 1.95 MB) fits the XCD's
// 4 MB L2 (R3: 648 MB FETCH = L2 thrash at 1.07 TB/s = the whole 620 us).
// Per n: geometry -> V[c][p] sampling (coalesced across c) -> GEMM 2o x 8p
// per thread (16 FMA per 2 coalesced weight loads + 2 broadcast ds_read_b128).
__global__ __launch_bounds__(256) __attribute__((amdgpu_waves_per_eu(1, 4)))
void deform_pool(const float* __restrict__ Ht,
        const float* __restrict__ OFF, const float* __restrict__ dwt,
        const float* __restrict__ db, float* __restrict__ pooledraw,
        float* __restrict__ sumsq4)
{
    __shared__ int   idx_s[32][8];
    __shared__ float g_s[32][8];
    __shared__ __align__(16) float Vb[128 * 36];   // [c][p], rows padded 32->36
    __shared__ float reds[128], redq[128];

    int fid = blockIdx.x;          // [0,800)
    int xcd = fid & 7;
    int local = fid >> 3;          // [0,100)
    if (local >= 98) return;
    int b = xcd >> 1;
    int d = (xcd & 1) * 14 + local / 7;
    int h0 = (local % 7) * 4;

    int t = threadIdx.x;
    int gp = t >> 3, gcr = t & 7;                 // geometry role
    int glh = gp >> 3, gw = gp & 7, gh = h0 + glh;
    int c2 = t & 127, half = t >> 7;              // phase2 role
    int l = t & 63, wvid = t >> 6;                // phase3 role

    float acc0[8], acc1[8];
    #pragma unroll
    for (int i = 0; i < 8; i++) { acc0[i] = 0.f; acc1[i] = 0.f; }

    const float* hb = Ht + (size_t)b * SP * 128;

    for (int n = 0; n < 27; n++) {
        __syncthreads();   // prev phase3 done with Vb / geom
        {   // ---- geometry for (n, gp, gcr) ----
            int kd = n / 9 - 1, kh = (n / 3) % 3 - 1, kw = n % 3 - 1;
            size_t obase = (size_t)b * 81 * SP + (size_t)d * 224 + gh * 8 + gw;
            float od  = OFF[obase + (size_t)n * SP];
            float oh  = OFF[obase + (size_t)(27 + n) * SP];
            float owv = OFF[obase + (size_t)(54 + n) * SP];
            float pd = fminf(fmaxf((float)(d + 1 + kd) + od, 0.f), 29.f);
            float ph = fminf(fmaxf((float)(gh + 1 + kh) + oh, 0.f), 29.f);
            float pw = fminf(fmaxf((float)(gw + 1 + kw) + owv, 0.f), 9.f);
            float qd = fminf(floorf(pd), 28.f);
            float qh = fminf(floorf(ph), 28.f);
            float qw = fminf(floorf(pw), 8.f);
            float td = fminf(pd - qd, 1.f);
            float th = fminf(ph - qh, 1.f);
            float tw = fminf(pw - qw, 1.f);
            int iqd = (int)qd - 1, iqh = (int)qh - 1, iqw = (int)qw - 1;
            int i = gcr >> 2, j = (gcr >> 1) & 1, k = gcr & 1;
            int du = iqd + i, hu = iqh + j, wu = iqw + k;
            bool val = (unsigned)du < 28u && (unsigned)hu < 28u && (unsigned)wu < 8u;
            float gg = (i ? td : 1.f - td) * (j ? th : 1.f - th) * (k ? tw : 1.f - tw);
            idx_s[gp][gcr] = val ? (du * 224 + hu * 8 + wu) : 0;
            g_s[gp][gcr] = val ? gg : 0.f;   // pad corners contribute 0
        }
        __syncthreads();
        // ---- phase 2: V[c][p] trilinear sample, coalesced across c ----
        #pragma unroll
        for (int q4 = 0; q4 < 4; q4++) {
            float v4[4];
            #pragma unroll
            for (int q = 0; q < 4; q++) {
                int p = half * 16 + q4 * 4 + q;
                float v = 0.f;
                #pragma unroll
                for (int cr = 0; cr < 8; cr++) {
                    int id = idx_s[p][cr];
                    float gg = g_s[p][cr];
                    v = fmaf(gg, hb[(size_t)id * 128 + c2], v);
                }
                v4[q] = v;
            }
            *(float4*)&Vb[c2 * 36 + half * 16 + q4 * 4] =
                make_float4(v4[0], v4[1], v4[2], v4[3]);
        }
        __syncthreads();
        // ---- phase 3: out[o][p] += sum_c dwt[n][c][o] * V[c][p] ----
        const float* wp = dwt + (size_t)n * 16384 + l;
        #pragma unroll 4
        for (int c = 0; c < 128; c++) {
            float w0 = wp[(size_t)c * 128];
            float w1 = wp[(size_t)c * 128 + 64];
            float4 va  = *(const float4*)&Vb[c * 36 + wvid * 8];
            float4 vb4 = *(const float4*)&Vb[c * 36 + wvid * 8 + 4];
            acc0[0] = fmaf(w0, va.x, acc0[0]);   acc1[0] = fmaf(w1, va.x, acc1[0]);
            acc0[1] = fmaf(w0, va.y, acc0[1]);   acc1[1] = fmaf(w1, va.y, acc1[1]);
            acc0[2] = fmaf(w0, va.z, acc0[2]);   acc1[2] = fmaf(w1, va.z, acc1[2]);
            acc0[3] = fmaf(w0, va.w, acc0[3]);   acc1[3] = fmaf(w1, va.w, acc1[3]);
            acc0[4] = fmaf(w0, vb4.x, acc0[4]);  acc1[4] = fmaf(w1, vb4.x, acc1[4]);
            acc0[5] = fmaf(w0, vb4.y, acc0[5]);  acc1[5] = fmaf(w1, vb4.y, acc1[5]);
            acc0[6] = fmaf(w0, vb4.z, acc0[6]);  acc1[6] = fmaf(w1, vb4.z, acc1[6]);
            acc0[7] = fmaf(w0, vb4.w, acc0[7]);  acc1[7] = fmaf(w1, vb4.w, acc1[7]);
        }
    }

    // ---- epilogue: bias + relu + pooled sum / sumsq ----
    float bo0 = db[l], bo1 = db[l + 64];
    float s0 = 0.f, q0 = 0.f, s1 = 0.f, q1 = 0.f;
    #pragma unroll
    for (int i = 0; i < 8; i++) {
        float v0 = fmaxf(acc0[i] + bo0, 0.f);
        float v1 = fmaxf(acc1[i] + bo1, 0.f);
        s0 += v0; q0 += v0 * v0;
        s1 += v1; q1 += v1 * v1;
    }
    __syncthreads();
    if (t < 128) { reds[t] = 0.f; redq[t] = 0.f; }
    __syncthreads();
    atomicAdd(&reds[l], s0);       atomicAdd(&redq[l], q0);
    atomicAdd(&reds[l + 64], s1);  atomicAdd(&redq[l + 64], q1);
    __syncthreads();
    if (t < 128) {
        atomicAdd(&pooledraw[b * 128 + t], reds[t]);
        atomicAdd(&sumsq4[t], redq[t]);
    }
}

// ---------------- BN4-folded pooling + FC + log_softmax ----------------
__global__ __launch_bounds__(256) void final_head(const float* __restrict__ pooledraw,
        const float* __restrict__ sumsq4, const float* __restrict__ g4,
        const float* __restrict__ b4, const float* __restrict__ fcw,
        const float* __restrict__ fcb, float* __restrict__ out)
{
    __shared__ float pooled_s[4][128];
    __shared__ float logits[4][10];
    int t = threadIdx.x;
    if (t < 128) {
        float s0 = pooledraw[t], s1 = pooledraw[128 + t];
        float s2 = pooledraw[256 + t], s3 = pooledraw[384 + t];
        float tot = s0 + s1 + s2 + s3;
        float m  = tot * (1.f / NSP);
        float v  = sumsq4[t] * (1.f / NSP) - m * m;
        float sc = g4[t] * rsqrtf(v + EPS);
        float sh = b4[t] - m * sc;
        pooled_s[0][t] = s0 * (1.f / SP) * sc + sh;
        pooled_s[1][t] = s1 * (1.f / SP) * sc + sh;
        pooled_s[2][t] = s2 * (1.f / SP) * sc + sh;
        pooled_s[3][t] = s3 * (1.f / SP) * sc + sh;
    }
    __syncthreads();
    if (t < 40) {
        int b = t / 10, j = t % 10;
        float l = fcb[j];
        for (int c = 0; c < 128; c++) l = fmaf(pooled_s[b][c], fcw[j * 128 + c], l);
        logits[b][j] = l;
    }
    __syncthreads();
    if (t < 4) {
        float mx = -1e30f;
        for (int j = 0; j < 10; j++) mx = fmaxf(mx, logits[t][j]);
        float se = 0.f;
        for (int j = 0; j < 10; j++) se += expf(logits[t][j] - mx);
        float lse = mx + logf(se);
        for (int j = 0; j < 10; j++) out[t * 10 + j] = logits[t][j] - lse;
    }
}

extern "C" void kernel_launch(void* const* d_in, const int* in_sizes, int n_in,
                              void* d_out, int out_size, void* d_ws, size_t ws_size,
                              hipStream_t stream)
{
    (void)in_sizes; (void)n_in; (void)out_size; (void)ws_size;
    const float* x   = (const float*)d_in[0];
    const float* c1w = (const float*)d_in[1];
    const float* c1b = (const float*)d_in[2];
    const float* g1  = (const float*)d_in[3];
    const float* b1  = (const float*)d_in[4];
    const float* c2w = (const float*)d_in[5];
    const float* c2b = (const float*)d_in[6];
    const float* g2  = (const float*)d_in[7];
    const float* b2  = (const float*)d_in[8];
    const float* c3w = (const float*)d_in[9];
    const float* c3b = (const float*)d_in[10];
    const float* g3  = (const float*)d_in[11];
    const float* b3  = (const float*)d_in[12];
    const float* ow  = (const float*)d_in[13];
    const float* ob  = (const float*)d_in[14];
    const float* dw  = (const float*)d_in[15];
    const float* db  = (const float*)d_in[16];
    const float* g4  = (const float*)d_in[17];
    const float* b4  = (const float*)d_in[18];
    const float* fcw = (const float*)d_in[19];
    const float* fcb = (const float*)d_in[20];

    float* ws = (float*)d_ws;
    float* S1 = ws + 0,   *Q1 = ws + 32;
    float* S2 = ws + 96,  *Q2 = ws + 160;
    float* S3 = ws + 224, *Q3 = ws + 352;
    float* PO = ws + 480;   // 4*128
    float* Q4 = ws + 992;   // 128
    float* y1  = ws + 2048;            // 4*32*6272
    float* y2  = y1 + 802816;          // 4*64*6272
    float* y3  = y2 + 1605632;         // 4*128*6272
    float* h3t = y3 + 3211264;         // channel-minor copy of h3
    float* dwt = h3t + 3211264;        // 27*128*128

    float* outf = (float*)d_out;
    float* offs = outf + 40;           // second output: offsets (4,81,28,28,8)

    hipMemsetAsync(ws, 0, 2048 * sizeof(float), stream);
    transpose_dw<<<1728, 256, 0, stream>>>(dw, dwt);

    conv3x3<1, 32, 8, true, true><<<dim3(104, 4), 256, 0, stream>>>(x, c1w, c1b, y1, S1, Q1);
    bn_apply<false><<<3136, 256, 0, stream>>>(y1, S1, Q1, g1, b1, 32, nullptr);

    conv3x3<32, 64, 8, true, true><<<dim3(104, 8), 256, 0, stream>>>(y1, c2w, c2b, y2, S2, Q2);
    bn_apply<false><<<6272, 256, 0, stream>>>(y2, S2, Q2, g2, b2, 64, nullptr);

    conv3x3<64, 128, 8, true, true><<<dim3(104, 16), 256, 0, stream>>>(y2, c3w, c3b, y3, S3, Q3);
    bn_apply<true><<<12544, 256, 0, stream>>>(y3, S3, Q3, g3, b3, 128, h3t);

    conv3x3<128, 81, 9, false, false><<<dim3(104, 9), 256, 0, stream>>>(y3, ow, ob, offs,
                                                                         nullptr, nullptr);
    deform_pool<<<800, 256, 0, stream>>>(h3t, offs, dwt, db, PO, Q4);
    final_head<<<1, 256, 0, stream>>>(PO, Q4, g4, b4, fcw, fcb, outf);
}